// Round 17
// baseline (202.865 us; speedup 1.0000x reference)
//
#include <hip/hip_runtime.h>
#include <hip/hip_fp16.h>
#include <stdint.h>

// GCN: out = relu(Ahat @ (X W1) + b1) -> relu(Ahat @ (. W2) + b2) -> @ Wfc + bfc
// Ahat = D^-1/2 (A+I) D^-1/2.
// Identity: layer(v) = dis[v] * ( sum_{e: dst=v} hs[src_e] + hs[v] ),
// hs[i] = (x[i] @ W) * dis[i].  Self-loops analytic.
//
// Cost model (R1..R16 measured):
//  - atomic-free CSR aggregation (R6), fp16 hs tables < 4MB XCD L2 (R8);
//  - launch gaps are cheaper than grid.sync (~150us/sync, R11);
//    cross-block re-reads cost HBM, not L2 (R13);
//  - aggs: L2 random-request-rate bound (R9 instr-halving neutral);
//  - sort: LDS-atomic ISSUE rate bound (R14/R15 neutral) -> only more
//    active CUs divide it; grid=196 left 60 of 256 CUs idle.
// R16->R17 FIX: K=261 > blockDim=256 broke every `if (t < K)` single-shot
// section in partition (buckets 256-260 got garbage gbase -> OOB recs write
// -> HSA fault). All per-bucket sections are now 256-strided loops.

constexpr int F = 16;
constexpr int K_MAX = 264;           // max partition buckets
constexpr int BN = 384;              // nodes per bucket (dst / 384)
constexpr int PT = 4096;             // edges per partition tile (16/thread)
constexpr int NPB = 32;              // nodes per block in aggregation
constexpr unsigned int CAP = 14336;  // bucket capacity (mean 12288, +18 sigma)

__device__ __forceinline__ float2 h2f2(__half2 h) { return __half22float2(h); }
__device__ __forceinline__ unsigned int bkt384(unsigned int d) {
    return ((d >> 7) * 43691u) >> 17;             // exact (d>>7)/3 for d>>7 < 2^17
}

// ---- pass 1: deterministic tile partition, grouped by bucket ------------
// rec = (dst_local << 17) | src   (N < 2^17, dst_local < 384)
// gcur holds RELATIVE cursors (memset 0); absolute base = b*CAP + cursor.
__global__ void __launch_bounds__(256)
partition_kernel(const int* __restrict__ src, const int* __restrict__ dst,
                 unsigned int* __restrict__ gcur, unsigned int* __restrict__ recs,
                 int E, int K) {
    __shared__ unsigned int hist[K_MAX * 4];
    __shared__ unsigned int offs[K_MAX * 4];
    __shared__ unsigned int bbase[K_MAX];     // per-bucket tile-local base
    __shared__ unsigned int gbase[K_MAX];
    __shared__ unsigned int drec[PT];
    __shared__ unsigned short dbuk[PT];       // bucket ids up to 260 -> u16
    const int t = threadIdx.x;
    const int tile0 = blockIdx.x * PT;
    const int cnt = min(PT, E - tile0);
    const unsigned int myc = (unsigned int)(t & 3);
    for (int i = t; i < K * 4; i += 256) hist[i] = 0u;
    __syncthreads();
    unsigned int rec[16], bp[16];
#pragma unroll
    for (int k = 0; k < 16; ++k) {
        int i = t + k * 256;                      // coalesced
        bp[k] = 0xFFFFFFFFu;
        if (i < cnt) {
            int e = tile0 + i;
            unsigned int d = (unsigned int)dst[e];
            unsigned int s = (unsigned int)src[e];
            unsigned int b = bkt384(d);
            rec[k] = ((d - b * (unsigned int)BN) << 17) | s;
            unsigned int pos = atomicAdd(&hist[b * 4 + myc], 1u);  // pos < 1024
            bp[k] = (b << 14) | (myc << 12) | pos;
        }
    }
    __syncthreads();
    for (int i = t; i < K; i += 256) {            // STRIDED (K may exceed 256)
        unsigned int h0 = hist[i * 4 + 0], h1 = hist[i * 4 + 1];
        unsigned int h2 = hist[i * 4 + 2], h3 = hist[i * 4 + 3];
        unsigned int tot = h0 + h1 + h2 + h3;
        bbase[i] = tot;                           // temp: bucket totals
        offs[i * 4 + 0] = 0u;
        offs[i * 4 + 1] = h0;
        offs[i * 4 + 2] = h0 + h1;
        offs[i * 4 + 3] = h0 + h1 + h2;
        gbase[i] = (unsigned int)i * CAP + atomicAdd(&gcur[i], tot);
    }
    __syncthreads();
    if (t == 0) {
        unsigned int run = 0;
        for (int i = 0; i < K; ++i) { unsigned int tmp = bbase[i]; bbase[i] = run; run += tmp; }
    }
    __syncthreads();
    for (int i = t; i < K; i += 256) {            // STRIDED
        unsigned int bb = bbase[i];
#pragma unroll
        for (int c = 0; c < 4; ++c) offs[i * 4 + c] += bb;
    }
    __syncthreads();
#pragma unroll
    for (int k = 0; k < 16; ++k) {
        if (bp[k] != 0xFFFFFFFFu) {
            unsigned int b = bp[k] >> 14, c = (bp[k] >> 12) & 3u, pos = bp[k] & 0xFFFu;
            unsigned int idx = offs[b * 4 + c] + pos;
            drec[idx] = rec[k];
            dbuk[idx] = (unsigned short)b;
        }
    }
    __syncthreads();
    for (int i = t; i < cnt; i += 256) {          // coalesced within runs
        unsigned int b = dbuk[i];
        recs[gbase[b] + ((unsigned int)i - bbase[b])] = drec[i];
    }
}

// ---- pass 2: counting sort -> CSR + dis + packed rows + fused mv --------
// 1024 threads/block, one block per bucket (grid 261 -> all 256 CUs busy).
// Single pass over recs (R13: re-reads cost HBM). 2-copy counters (R15).
__global__ void __launch_bounds__(1024)
sort_mv_kernel(const unsigned int* __restrict__ recs, const unsigned int* __restrict__ gcur,
               const float* __restrict__ x, const float* __restrict__ W1,
               float* __restrict__ dis, unsigned int* __restrict__ rp,
               unsigned int* __restrict__ recs2, __half* __restrict__ hs1, int N) {
    __shared__ unsigned int cnt0[BN];
    __shared__ unsigned int cnt1[BN];
    __shared__ unsigned int wsum[6];
    __shared__ float sdis[BN];
    __shared__ float ws[16][16];
    __shared__ float xs[64][17];
    const int b = blockIdx.x;
    const int t = threadIdx.x;
    const int lane = t & 63, wid = t >> 6;
    if (t < BN) { cnt0[t] = 0u; cnt1[t] = 0u; }
    if (t < 256) ws[t >> 4][t & 15] = W1[t];
    __syncthreads();
    const unsigned int e0 = (unsigned int)b * CAP;
    const unsigned int e1 = e0 + gcur[b];         // bucket end (relative cursor)
    unsigned int* mycnt = (t & 1) ? cnt1 : cnt0;
    for (unsigned int e = e0 + t; e < e1; e += 1024)
        atomicAdd(&mycnt[recs[e] >> 17], 1u);     // native u32 LDS
    __syncthreads();
    // block-scan of 384 degrees using first 6 waves
    unsigned int c = 0, c0v = 0, xsc = 0;
    if (t < BN) {
        c0v = cnt0[t];
        c = c0v + cnt1[t];
        xsc = c;
#pragma unroll
        for (int o = 1; o < 64; o <<= 1) {
            unsigned int y = __shfl_up(xsc, o, 64);
            if (lane >= o) xsc += y;
        }
        if (lane == 63) wsum[wid] = xsc;
    }
    __syncthreads();
    if (t == 0) {
        unsigned int run = 0;
#pragma unroll
        for (int i = 0; i < 6; ++i) { unsigned int tmp = wsum[i]; wsum[i] = run; run += tmp; }
    }
    __syncthreads();
    if (t < BN) {
        const unsigned int start = e0 + wsum[wid] + xsc - c;   // exclusive prefix
        const int v = b * BN + t;
        const float dv = rsqrtf(1.0f + (float)c);
        sdis[t] = dv;
        if (v < N) {
            dis[v] = dv;
            rp[v] = (c << 24) | start;            // start < 261*14336=3.74M < 2^24
        }
        cnt0[t] = start;                          // copy-0 cursor range
        cnt1[t] = start + c0v;                    // copy-1 cursor range
    }
    __syncthreads();
    for (unsigned int e = e0 + t; e < e1; e += 1024) {
        unsigned int r = recs[e];                            // coalesced single read
        unsigned int slot = atomicAdd(&mycnt[r >> 17], 1u);  // 2-copy cursors
        recs2[slot] = r & 0x1FFFFu;                          // src only
    }
    // ---- fused mv: hs1 for this block's 384 nodes (64 nodes/pass) -------
    const int n = t >> 4, j = t & 15;
#pragma unroll
    for (int tile = 0; tile < 6; ++tile) {
        const int loc = tile * 64 + n;
        const int node = b * BN + loc;
        __syncthreads();
        xs[n][j] = (node < N) ? x[(size_t)node * F + j] : 0.0f;
        __syncthreads();
        float acc = 0.f;
#pragma unroll
        for (int k = 0; k < 16; ++k) acc += xs[n][k] * ws[k][j];
        if (node < N) hs1[(size_t)node * F + j] = __float2half(acc * sdis[loc]);
    }
}

// ---- layer-1 aggregation + relu + W2 matvec (zero atomics) --------------
// 8-lane __half2 groups; NPB=32 nodes/block -> grid 3125 (~12 blocks/CU).
__global__ void __launch_bounds__(256)
agg1_kernel(const unsigned int* __restrict__ recs2, const unsigned int* __restrict__ rp,
            const __half2* __restrict__ hs1, const float* __restrict__ dis,
            const float* __restrict__ W2, const float* __restrict__ b1,
            __half* __restrict__ hs2, int N) {
    __shared__ float ws[16][16];
    __shared__ float hbf[NPB][17];
    const int t = threadIdx.x;
    ws[t >> 4][t & 15] = W2[t];
    const int j2 = t & 7;
    const int g8 = t >> 3;
    const int v0 = blockIdx.x * NPB;
    {
        const int v = v0 + g8;
        float sx = 0.f, sy = 0.f, dv = 0.f;
        if (v < N) {
            dv = dis[v];
            const unsigned int w = rp[v];
            unsigned int e = w & 0xFFFFFFu;
            const unsigned int e1 = e + (w >> 24);
            float2 s = h2f2(hs1[(size_t)v * 8 + j2]);       // self-loop term
            sx = s.x; sy = s.y;
            for (; e + 8 <= e1; e += 8) {                   // 8 independent rows
                unsigned int r0 = recs2[e + 0], r1 = recs2[e + 1];
                unsigned int r2 = recs2[e + 2], r3 = recs2[e + 3];
                unsigned int r4 = recs2[e + 4], r5 = recs2[e + 5];
                unsigned int r6 = recs2[e + 6], r7 = recs2[e + 7];
                float2 a0 = h2f2(hs1[r0 * 8 + j2]), a1 = h2f2(hs1[r1 * 8 + j2]);
                float2 a2 = h2f2(hs1[r2 * 8 + j2]), a3 = h2f2(hs1[r3 * 8 + j2]);
                float2 a4 = h2f2(hs1[r4 * 8 + j2]), a5 = h2f2(hs1[r5 * 8 + j2]);
                float2 a6 = h2f2(hs1[r6 * 8 + j2]), a7 = h2f2(hs1[r7 * 8 + j2]);
                sx += ((a0.x + a1.x) + (a2.x + a3.x)) + ((a4.x + a5.x) + (a6.x + a7.x));
                sy += ((a0.y + a1.y) + (a2.y + a3.y)) + ((a4.y + a5.y) + (a6.y + a7.y));
            }
            for (; e < e1; ++e) {
                float2 a = h2f2(hs1[recs2[e] * 8 + j2]);
                sx += a.x; sy += a.y;
            }
        }
        hbf[g8][2 * j2 + 0] = fmaxf(dv * sx + b1[2 * j2 + 0], 0.f);
        hbf[g8][2 * j2 + 1] = fmaxf(dv * sy + b1[2 * j2 + 1], 0.f);
    }
    __syncthreads();
    const int j = t & 15;
    const int g = t >> 4;
#pragma unroll
    for (int it = 0; it < 2; ++it) {
        const int n = g + 16 * it;
        const int v = v0 + n;
        if (v >= N) continue;
        float acc = 0.f;
#pragma unroll
        for (int k = 0; k < 16; ++k) acc += hbf[n][k] * ws[k][j];
        hs2[(size_t)v * F + j] = __float2half(acc * dis[v]);
    }
}

// ---- layer-2 aggregation + relu + FC head -------------------------------
__global__ void __launch_bounds__(256)
agg2_kernel(const unsigned int* __restrict__ recs2, const unsigned int* __restrict__ rp,
            const __half2* __restrict__ hs2, const float* __restrict__ dis,
            const float* __restrict__ b2, const float* __restrict__ Wfc,
            const float* __restrict__ bfc, float* __restrict__ out, int N) {
    const int t = threadIdx.x;
    const int j2 = t & 7;
    const int g8 = t >> 3;
    const int v0 = blockIdx.x * NPB;
    const float wfx = Wfc[2 * j2 + 0], wfy = Wfc[2 * j2 + 1];
    const float bbx = b2[2 * j2 + 0], bby = b2[2 * j2 + 1];
    const float bf = bfc[0];
    const int v = v0 + g8;
    if (v >= N) return;
    const unsigned int w = rp[v];
    unsigned int e = w & 0xFFFFFFu;
    const unsigned int e1 = e + (w >> 24);
    float2 s0 = h2f2(hs2[(size_t)v * 8 + j2]);
    float sx = s0.x, sy = s0.y;
    for (; e + 8 <= e1; e += 8) {
        unsigned int r0 = recs2[e + 0], r1 = recs2[e + 1];
        unsigned int r2 = recs2[e + 2], r3 = recs2[e + 3];
        unsigned int r4 = recs2[e + 4], r5 = recs2[e + 5];
        unsigned int r6 = recs2[e + 6], r7 = recs2[e + 7];
        float2 a0 = h2f2(hs2[r0 * 8 + j2]), a1 = h2f2(hs2[r1 * 8 + j2]);
        float2 a2 = h2f2(hs2[r2 * 8 + j2]), a3 = h2f2(hs2[r3 * 8 + j2]);
        float2 a4 = h2f2(hs2[r4 * 8 + j2]), a5 = h2f2(hs2[r5 * 8 + j2]);
        float2 a6 = h2f2(hs2[r6 * 8 + j2]), a7 = h2f2(hs2[r7 * 8 + j2]);
        sx += ((a0.x + a1.x) + (a2.x + a3.x)) + ((a4.x + a5.x) + (a6.x + a7.x));
        sy += ((a0.y + a1.y) + (a2.y + a3.y)) + ((a4.y + a5.y) + (a6.y + a7.y));
    }
    for (; e < e1; ++e) {
        float2 a = h2f2(hs2[recs2[e] * 8 + j2]);
        sx += a.x; sy += a.y;
    }
    const float dv = dis[v];
    float h = fmaxf(dv * sx + bbx, 0.f) * wfx + fmaxf(dv * sy + bby, 0.f) * wfy;
    h += __shfl_down(h, 4, 8);
    h += __shfl_down(h, 2, 8);
    h += __shfl_down(h, 1, 8);
    if (j2 == 0) out[v] = h + bf;
}

static inline char* align256(char* p) {
    return (char*)(((uintptr_t)p + 255) & ~(uintptr_t)255);
}

extern "C" void kernel_launch(void* const* d_in, const int* in_sizes, int n_in,
                              void* d_out, int out_size, void* d_ws, size_t ws_size,
                              hipStream_t stream) {
    const float* x   = (const float*)d_in[0];
    const int*   ei  = (const int*)d_in[1];
    const float* W1  = (const float*)d_in[2];
    const float* b1  = (const float*)d_in[3];
    const float* W2  = (const float*)d_in[4];
    const float* b2  = (const float*)d_in[5];
    const float* Wfc = (const float*)d_in[6];
    const float* bfc = (const float*)d_in[7];
    float* out = (float*)d_out;

    const int N = in_sizes[0] / F;        // 100000
    const int E = in_sizes[1] / 2;        // 3200000
    const int* src = ei;
    const int* dst = ei + E;
    const int K = (N + BN - 1) / BN;      // 261

    // 256-B-aligned layout (R2 lesson). hs1/hs2 NOT aliased with recs:
    // sort_mv writes hs1 while other blocks still read their recs.
    char* p = (char*)d_ws;
    float* dis = (float*)align256(p);                   p = (char*)(dis + N);
    unsigned int* gcur  = (unsigned int*)align256(p);   p = (char*)(gcur + K);
    unsigned int* rp    = (unsigned int*)align256(p);   p = (char*)(rp + N);
    unsigned int* recs2 = (unsigned int*)align256(p);   p = (char*)(recs2 + (size_t)K * CAP);
    unsigned int* recs  = (unsigned int*)align256(p);   p = (char*)(recs + (size_t)K * CAP);
    __half* hs1 = (__half*)align256(p);                 p = (char*)(hs1 + (size_t)N * F);
    __half* hs2 = (__half*)align256(p);

    const int T = 256;

    hipMemsetAsync(gcur, 0, (size_t)K * sizeof(unsigned int), stream);
    partition_kernel<<<(E + PT - 1) / PT, T, 0, stream>>>(src, dst, gcur, recs, E, K);
    sort_mv_kernel<<<K, 1024, 0, stream>>>(recs, gcur, x, W1, dis, rp, recs2, hs1, N);
    agg1_kernel<<<(N + NPB - 1) / NPB, T, 0, stream>>>(recs2, rp, (const __half2*)hs1, dis, W2, b1, hs2, N);
    agg2_kernel<<<(N + NPB - 1) / NPB, T, 0, stream>>>(recs2, rp, (const __half2*)hs2, dis, b2, Wfc, bfc, out, N);
}

// Round 18
// 191.537 us; speedup vs baseline: 1.0591x; 1.0591x over previous
//
#include <hip/hip_runtime.h>
#include <hip/hip_fp16.h>
#include <stdint.h>

// GCN: out = relu(Ahat @ (X W1) + b1) -> relu(Ahat @ (. W2) + b2) -> @ Wfc + bfc
// Ahat = D^-1/2 (A+I) D^-1/2.
// Identity: layer(v) = dis[v] * ( sum_{e: dst=v} hs[src_e] + hs[v] ),
// hs[i] = (x[i] @ W) * dis[i].  Self-loops analytic.
//
// Cost model (R1..R17 measured):
//  - atomic-free CSR aggregation (R6), fp16 hs tables < 4MB XCD L2 (R8);
//  - launch gaps are cheaper than grid.sync (~150us/sync, R11);
//    cross-block re-reads cost HBM, not L2 (R13);
//  - aggs: L2 random-request-rate bound (R9 instr-halving neutral);
//  - sort: DS-issue-rate bound, wave/contention-invariant (R14/R15);
//    wall time = ceil(K/256) x per-block time (R17: K=261 -> 5 CUs run 2
//    blocks -> regression; K=196 -> 60 CUs idle).
// R18: K=250 (BN=400): every CU <= 1 sort block, zero tail, per-block work
// x0.78 of K=196. Exact /400 via magic mul (d*167773)>>26. dbuk back to u8.

constexpr int F = 16;
constexpr int K_MAX = 256;           // max partition buckets
constexpr int BN = 400;              // nodes per bucket (dst / 400)
constexpr int PT = 4096;             // edges per partition tile (16/thread)
constexpr int NPB = 32;              // nodes per block in aggregation
constexpr unsigned int CAP = 14848;  // bucket capacity (mean 12800, +18 sigma)

__device__ __forceinline__ float2 h2f2(__half2 h) { return __half22float2(h); }
__device__ __forceinline__ unsigned int bkt400(unsigned int d) {
    return (unsigned int)(((unsigned long long)d * 167773ull) >> 26);  // exact d/400, d < 2^17
}

// ---- pass 1: deterministic tile partition, grouped by bucket ------------
// rec = (dst_local << 17) | src   (N < 2^17, dst_local < 400)
// gcur holds RELATIVE cursors (memset 0); absolute base = b*CAP + cursor.
__global__ void __launch_bounds__(256)
partition_kernel(const int* __restrict__ src, const int* __restrict__ dst,
                 unsigned int* __restrict__ gcur, unsigned int* __restrict__ recs,
                 int E, int K) {
    __shared__ unsigned int hist[K_MAX * 4];
    __shared__ unsigned int offs[K_MAX * 4];
    __shared__ unsigned int bbase[K_MAX];     // per-bucket tile-local base
    __shared__ unsigned int gbase[K_MAX];
    __shared__ unsigned int drec[PT];
    __shared__ unsigned char dbuk[PT];        // bucket ids < 250 -> u8
    const int t = threadIdx.x;
    const int tile0 = blockIdx.x * PT;
    const int cnt = min(PT, E - tile0);
    const unsigned int myc = (unsigned int)(t & 3);
    for (int i = t; i < K * 4; i += 256) hist[i] = 0u;
    __syncthreads();
    unsigned int rec[16], bp[16];
#pragma unroll
    for (int k = 0; k < 16; ++k) {
        int i = t + k * 256;                      // coalesced
        bp[k] = 0xFFFFFFFFu;
        if (i < cnt) {
            int e = tile0 + i;
            unsigned int d = (unsigned int)dst[e];
            unsigned int s = (unsigned int)src[e];
            unsigned int b = bkt400(d);
            rec[k] = ((d - b * (unsigned int)BN) << 17) | s;
            unsigned int pos = atomicAdd(&hist[b * 4 + myc], 1u);  // pos < 4096
            bp[k] = (b << 14) | (myc << 12) | pos;
        }
    }
    __syncthreads();
    for (int i = t; i < K; i += 256) {            // strided for safety
        unsigned int h0 = hist[i * 4 + 0], h1 = hist[i * 4 + 1];
        unsigned int h2 = hist[i * 4 + 2], h3 = hist[i * 4 + 3];
        unsigned int tot = h0 + h1 + h2 + h3;
        bbase[i] = tot;                           // temp: bucket totals
        offs[i * 4 + 0] = 0u;
        offs[i * 4 + 1] = h0;
        offs[i * 4 + 2] = h0 + h1;
        offs[i * 4 + 3] = h0 + h1 + h2;
        gbase[i] = (unsigned int)i * CAP + atomicAdd(&gcur[i], tot);
    }
    __syncthreads();
    if (t == 0) {
        unsigned int run = 0;
        for (int i = 0; i < K; ++i) { unsigned int tmp = bbase[i]; bbase[i] = run; run += tmp; }
    }
    __syncthreads();
    for (int i = t; i < K; i += 256) {
        unsigned int bb = bbase[i];
#pragma unroll
        for (int c = 0; c < 4; ++c) offs[i * 4 + c] += bb;
    }
    __syncthreads();
#pragma unroll
    for (int k = 0; k < 16; ++k) {
        if (bp[k] != 0xFFFFFFFFu) {
            unsigned int b = bp[k] >> 14, c = (bp[k] >> 12) & 3u, pos = bp[k] & 0xFFFu;
            unsigned int idx = offs[b * 4 + c] + pos;
            drec[idx] = rec[k];
            dbuk[idx] = (unsigned char)b;
        }
    }
    __syncthreads();
    for (int i = t; i < cnt; i += 256) {          // coalesced within runs
        unsigned int b = dbuk[i];
        recs[gbase[b] + ((unsigned int)i - bbase[b])] = drec[i];
    }
}

// ---- pass 2: counting sort -> CSR + dis + packed rows + fused mv --------
// 1024 threads/block, one block per bucket (grid 250 <= 256 CUs: no tail).
// Single pass over recs (R13: re-reads cost HBM). 2-copy counters (R15).
__global__ void __launch_bounds__(1024)
sort_mv_kernel(const unsigned int* __restrict__ recs, const unsigned int* __restrict__ gcur,
               const float* __restrict__ x, const float* __restrict__ W1,
               float* __restrict__ dis, unsigned int* __restrict__ rp,
               unsigned int* __restrict__ recs2, __half* __restrict__ hs1, int N) {
    __shared__ unsigned int cnt0[BN];
    __shared__ unsigned int cnt1[BN];
    __shared__ unsigned int wsum[7];
    __shared__ float sdis[BN];
    __shared__ float ws[16][16];
    __shared__ float xs[64][17];
    const int b = blockIdx.x;
    const int t = threadIdx.x;
    const int lane = t & 63, wid = t >> 6;
    if (t < BN) { cnt0[t] = 0u; cnt1[t] = 0u; }
    if (t < 256) ws[t >> 4][t & 15] = W1[t];
    __syncthreads();
    const unsigned int e0 = (unsigned int)b * CAP;
    const unsigned int e1 = e0 + gcur[b];         // bucket end (relative cursor)
    unsigned int* mycnt = (t & 1) ? cnt1 : cnt0;
    for (unsigned int e = e0 + t; e < e1; e += 1024)
        atomicAdd(&mycnt[recs[e] >> 17], 1u);     // native u32 LDS
    __syncthreads();
    // block-scan of 400 degrees using first 7 waves
    unsigned int c = 0, c0v = 0, xsc = 0;
    if (t < BN) {
        c0v = cnt0[t];
        c = c0v + cnt1[t];
        xsc = c;
#pragma unroll
        for (int o = 1; o < 64; o <<= 1) {
            unsigned int y = __shfl_up(xsc, o, 64);
            if (lane >= o) xsc += y;
        }
        if (lane == 63 || t == BN - 1) wsum[wid] = xsc;
    }
    __syncthreads();
    if (t == 0) {
        unsigned int run = 0;
#pragma unroll
        for (int i = 0; i < 7; ++i) { unsigned int tmp = wsum[i]; wsum[i] = run; run += tmp; }
    }
    __syncthreads();
    if (t < BN) {
        const unsigned int start = e0 + wsum[wid] + xsc - c;   // exclusive prefix
        const int v = b * BN + t;
        const float dv = rsqrtf(1.0f + (float)c);
        sdis[t] = dv;
        if (v < N) {
            dis[v] = dv;
            rp[v] = (c << 24) | start;            // start < 250*14848=3.71M < 2^24
        }
        cnt0[t] = start;                          // copy-0 cursor range
        cnt1[t] = start + c0v;                    // copy-1 cursor range
    }
    __syncthreads();
    for (unsigned int e = e0 + t; e < e1; e += 1024) {
        unsigned int r = recs[e];                            // coalesced single read
        unsigned int slot = atomicAdd(&mycnt[r >> 17], 1u);  // 2-copy cursors
        recs2[slot] = r & 0x1FFFFu;                          // src only
    }
    // ---- fused mv: hs1 for this block's 400 nodes (64 nodes/pass) -------
    const int n = t >> 4, j = t & 15;
#pragma unroll
    for (int tile = 0; tile < 7; ++tile) {
        const int loc = tile * 64 + n;
        const int node = b * BN + loc;
        __syncthreads();
        xs[n][j] = (loc < BN && node < N) ? x[(size_t)node * F + j] : 0.0f;
        __syncthreads();
        if (loc < BN && node < N) {
            float acc = 0.f;
#pragma unroll
            for (int k = 0; k < 16; ++k) acc += xs[n][k] * ws[k][j];
            hs1[(size_t)node * F + j] = __float2half(acc * sdis[loc]);
        }
    }
}

// ---- layer-1 aggregation + relu + W2 matvec (zero atomics) --------------
// 8-lane __half2 groups; NPB=32 nodes/block -> grid 3125 (~12 blocks/CU).
__global__ void __launch_bounds__(256)
agg1_kernel(const unsigned int* __restrict__ recs2, const unsigned int* __restrict__ rp,
            const __half2* __restrict__ hs1, const float* __restrict__ dis,
            const float* __restrict__ W2, const float* __restrict__ b1,
            __half* __restrict__ hs2, int N) {
    __shared__ float ws[16][16];
    __shared__ float hbf[NPB][17];
    const int t = threadIdx.x;
    ws[t >> 4][t & 15] = W2[t];
    const int j2 = t & 7;
    const int g8 = t >> 3;
    const int v0 = blockIdx.x * NPB;
    {
        const int v = v0 + g8;
        float sx = 0.f, sy = 0.f, dv = 0.f;
        if (v < N) {
            dv = dis[v];
            const unsigned int w = rp[v];
            unsigned int e = w & 0xFFFFFFu;
            const unsigned int e1 = e + (w >> 24);
            float2 s = h2f2(hs1[(size_t)v * 8 + j2]);       // self-loop term
            sx = s.x; sy = s.y;
            for (; e + 8 <= e1; e += 8) {                   // 8 independent rows
                unsigned int r0 = recs2[e + 0], r1 = recs2[e + 1];
                unsigned int r2 = recs2[e + 2], r3 = recs2[e + 3];
                unsigned int r4 = recs2[e + 4], r5 = recs2[e + 5];
                unsigned int r6 = recs2[e + 6], r7 = recs2[e + 7];
                float2 a0 = h2f2(hs1[r0 * 8 + j2]), a1 = h2f2(hs1[r1 * 8 + j2]);
                float2 a2 = h2f2(hs1[r2 * 8 + j2]), a3 = h2f2(hs1[r3 * 8 + j2]);
                float2 a4 = h2f2(hs1[r4 * 8 + j2]), a5 = h2f2(hs1[r5 * 8 + j2]);
                float2 a6 = h2f2(hs1[r6 * 8 + j2]), a7 = h2f2(hs1[r7 * 8 + j2]);
                sx += ((a0.x + a1.x) + (a2.x + a3.x)) + ((a4.x + a5.x) + (a6.x + a7.x));
                sy += ((a0.y + a1.y) + (a2.y + a3.y)) + ((a4.y + a5.y) + (a6.y + a7.y));
            }
            for (; e < e1; ++e) {
                float2 a = h2f2(hs1[recs2[e] * 8 + j2]);
                sx += a.x; sy += a.y;
            }
        }
        hbf[g8][2 * j2 + 0] = fmaxf(dv * sx + b1[2 * j2 + 0], 0.f);
        hbf[g8][2 * j2 + 1] = fmaxf(dv * sy + b1[2 * j2 + 1], 0.f);
    }
    __syncthreads();
    const int j = t & 15;
    const int g = t >> 4;
#pragma unroll
    for (int it = 0; it < 2; ++it) {
        const int n = g + 16 * it;
        const int v = v0 + n;
        if (v >= N) continue;
        float acc = 0.f;
#pragma unroll
        for (int k = 0; k < 16; ++k) acc += hbf[n][k] * ws[k][j];
        hs2[(size_t)v * F + j] = __float2half(acc * dis[v]);
    }
}

// ---- layer-2 aggregation + relu + FC head -------------------------------
__global__ void __launch_bounds__(256)
agg2_kernel(const unsigned int* __restrict__ recs2, const unsigned int* __restrict__ rp,
            const __half2* __restrict__ hs2, const float* __restrict__ dis,
            const float* __restrict__ b2, const float* __restrict__ Wfc,
            const float* __restrict__ bfc, float* __restrict__ out, int N) {
    const int t = threadIdx.x;
    const int j2 = t & 7;
    const int g8 = t >> 3;
    const int v0 = blockIdx.x * NPB;
    const float wfx = Wfc[2 * j2 + 0], wfy = Wfc[2 * j2 + 1];
    const float bbx = b2[2 * j2 + 0], bby = b2[2 * j2 + 1];
    const float bf = bfc[0];
    const int v = v0 + g8;
    if (v >= N) return;
    const unsigned int w = rp[v];
    unsigned int e = w & 0xFFFFFFu;
    const unsigned int e1 = e + (w >> 24);
    float2 s0 = h2f2(hs2[(size_t)v * 8 + j2]);
    float sx = s0.x, sy = s0.y;
    for (; e + 8 <= e1; e += 8) {
        unsigned int r0 = recs2[e + 0], r1 = recs2[e + 1];
        unsigned int r2 = recs2[e + 2], r3 = recs2[e + 3];
        unsigned int r4 = recs2[e + 4], r5 = recs2[e + 5];
        unsigned int r6 = recs2[e + 6], r7 = recs2[e + 7];
        float2 a0 = h2f2(hs2[r0 * 8 + j2]), a1 = h2f2(hs2[r1 * 8 + j2]);
        float2 a2 = h2f2(hs2[r2 * 8 + j2]), a3 = h2f2(hs2[r3 * 8 + j2]);
        float2 a4 = h2f2(hs2[r4 * 8 + j2]), a5 = h2f2(hs2[r5 * 8 + j2]);
        float2 a6 = h2f2(hs2[r6 * 8 + j2]), a7 = h2f2(hs2[r7 * 8 + j2]);
        sx += ((a0.x + a1.x) + (a2.x + a3.x)) + ((a4.x + a5.x) + (a6.x + a7.x));
        sy += ((a0.y + a1.y) + (a2.y + a3.y)) + ((a4.y + a5.y) + (a6.y + a7.y));
    }
    for (; e < e1; ++e) {
        float2 a = h2f2(hs2[recs2[e] * 8 + j2]);
        sx += a.x; sy += a.y;
    }
    const float dv = dis[v];
    float h = fmaxf(dv * sx + bbx, 0.f) * wfx + fmaxf(dv * sy + bby, 0.f) * wfy;
    h += __shfl_down(h, 4, 8);
    h += __shfl_down(h, 2, 8);
    h += __shfl_down(h, 1, 8);
    if (j2 == 0) out[v] = h + bf;
}

static inline char* align256(char* p) {
    return (char*)(((uintptr_t)p + 255) & ~(uintptr_t)255);
}

extern "C" void kernel_launch(void* const* d_in, const int* in_sizes, int n_in,
                              void* d_out, int out_size, void* d_ws, size_t ws_size,
                              hipStream_t stream) {
    const float* x   = (const float*)d_in[0];
    const int*   ei  = (const int*)d_in[1];
    const float* W1  = (const float*)d_in[2];
    const float* b1  = (const float*)d_in[3];
    const float* W2  = (const float*)d_in[4];
    const float* b2  = (const float*)d_in[5];
    const float* Wfc = (const float*)d_in[6];
    const float* bfc = (const float*)d_in[7];
    float* out = (float*)d_out;

    const int N = in_sizes[0] / F;        // 100000
    const int E = in_sizes[1] / 2;        // 3200000
    const int* src = ei;
    const int* dst = ei + E;
    const int K = (N + BN - 1) / BN;      // 250

    // 256-B-aligned layout (R2 lesson). hs1/hs2 NOT aliased with recs:
    // sort_mv writes hs1 while other blocks still read their recs.
    char* p = (char*)d_ws;
    float* dis = (float*)align256(p);                   p = (char*)(dis + N);
    unsigned int* gcur  = (unsigned int*)align256(p);   p = (char*)(gcur + K);
    unsigned int* rp    = (unsigned int*)align256(p);   p = (char*)(rp + N);
    unsigned int* recs2 = (unsigned int*)align256(p);   p = (char*)(recs2 + (size_t)K * CAP);
    unsigned int* recs  = (unsigned int*)align256(p);   p = (char*)(recs + (size_t)K * CAP);
    __half* hs1 = (__half*)align256(p);                 p = (char*)(hs1 + (size_t)N * F);
    __half* hs2 = (__half*)align256(p);

    const int T = 256;

    hipMemsetAsync(gcur, 0, (size_t)K * sizeof(unsigned int), stream);
    partition_kernel<<<(E + PT - 1) / PT, T, 0, stream>>>(src, dst, gcur, recs, E, K);
    sort_mv_kernel<<<K, 1024, 0, stream>>>(recs, gcur, x, W1, dis, rp, recs2, hs1, N);
    agg1_kernel<<<(N + NPB - 1) / NPB, T, 0, stream>>>(recs2, rp, (const __half2*)hs1, dis, W2, b1, hs2, N);
    agg2_kernel<<<(N + NPB - 1) / NPB, T, 0, stream>>>(recs2, rp, (const __half2*)hs2, dis, b2, Wfc, bfc, out, N);
}